// Round 10
// baseline (179.774 us; speedup 1.0000x reference)
//
#include <hip/hip_runtime.h>
#include <hip/hip_bf16.h>

typedef __bf16 bf16_t;
typedef __bf16 bf16x8 __attribute__((ext_vector_type(8)));
typedef float f32x4 __attribute__((ext_vector_type(4)));
typedef int i32x4 __attribute__((ext_vector_type(4)));

#define S_TOT 12288
#define F_IN 128
#define F_OUT 256
#define EPS 1e-5f

static __device__ __forceinline__ float silu_f(float v) {
  return v / (1.0f + __expf(-v));
}

static __device__ __forceinline__ void gll16(const bf16_t* g, bf16_t* l) {
  __builtin_amdgcn_global_load_lds(
      (const __attribute__((address_space(1))) void*)(const void*)g,
      (__attribute__((address_space(3))) void*)(void*)l, 16, 0, 0);
}

// ---------------- prep: pack weights (blocks 0..447) + GN1 stats (448..639) ----
// CHUNK-MAJOR pack: kcg = chunk*9 + tap. Unit (kcg, cb): lane l holds
// B[f=32*chunk+8*(l>>4)+j of W_tap][o=16cb+(l&15)] at unit*1024B + l*16B.
__global__ void prep_kernel(const float* __restrict__ W1,
                            const float* __restrict__ W2,
                            const float* __restrict__ Wsk,
                            bf16_t* __restrict__ W1p,
                            bf16_t* __restrict__ W2p,
                            bf16_t* __restrict__ Wsp,
                            const float* __restrict__ x,
                            float* __restrict__ sum1, float* __restrict__ ss1) {
  __shared__ float gs[32], gq[32];
  if (blockIdx.x < 448) {
    int w = blockIdx.x * 4 + (threadIdx.x >> 6);
    int l = threadIdx.x & 63;
    int lo = l & 15, hi = l >> 4;
    const float* src;
    bf16_t* dst;
    int fbase, obase;
    if (w < 576) {
      int kcg = w >> 4, cb = w & 15;
      int tap = kcg % 9, chunk = kcg / 9;
      src = W1 + tap * 32768;
      dst = W1p + (size_t)w * 512;
      fbase = 32 * chunk + 8 * hi; obase = 16 * cb + lo;
    } else if (w < 1728) {
      int idx = w - 576;
      int kcg = idx >> 4, cb = idx & 15;
      int tap = kcg % 9, chunk = kcg / 9;
      src = W2 + tap * 65536;
      dst = W2p + (size_t)idx * 512;
      fbase = 32 * chunk + 8 * hi; obase = 16 * cb + lo;
    } else {
      int idx = w - 1728;
      int kc = idx >> 4, cb = idx & 15;
      src = Wsk;
      dst = Wsp + (size_t)idx * 512;
      fbase = 32 * kc + 8 * hi; obase = 16 * cb + lo;
    }
    bf16x8 v;
#pragma unroll
    for (int j = 0; j < 8; ++j)
      v[j] = (bf16_t)src[(fbase + j) * 256 + obase];
    *(bf16x8*)(dst + l * 8) = v;
  } else {
    int blk = blockIdx.x - 448;
    int vt = blk & 3;
    int s0 = (blk >> 2) * 256;
    int t = threadIdx.x;
    int col = t & 31, ro = t >> 5;
    float s_ = 0.f, q_ = 0.f;
    const f32x4* xp = (const f32x4*)(x + ((size_t)vt * S_TOT + s0) * F_IN);
#pragma unroll 4
    for (int it = 0; it < 32; ++it) {
      f32x4 v = xp[(size_t)(it * 8 + ro) * 32 + col];
      s_ += v[0] + v[1] + v[2] + v[3];
      q_ += v[0]*v[0] + v[1]*v[1] + v[2]*v[2] + v[3]*v[3];
    }
    if (t < 32) { gs[t] = 0.f; gq[t] = 0.f; }
    __syncthreads();
    atomicAdd(&gs[col], s_);
    atomicAdd(&gq[col], q_);
    __syncthreads();
    if (t < 32) {
      atomicAdd(&sum1[vt * 32 + t], gs[t]);
      atomicAdd(&ss1[vt * 32 + t], gq[t]);
    }
  }
}

// ---------------- apply GN1 (affine inline) + SiLU -> h1 ----------------
__global__ void apply_gn1(const float* __restrict__ x,
                          const float* __restrict__ sum1, const float* __restrict__ ss1,
                          const float* __restrict__ gs, const float* __restrict__ gb,
                          bf16_t* __restrict__ h1) {
  size_t base = ((size_t)blockIdx.x * 256 + threadIdx.x) * 8;
  int vt = (int)(base / ((size_t)S_TOT * F_IN));
  int c0 = (int)(base & (F_IN - 1));
  const f32x4* xp = (const f32x4*)(x + base);
  f32x4 v0 = xp[0], v1 = xp[1];
  float N = (float)(S_TOT * 4);
  bf16x8 o;
#pragma unroll
  for (int gi = 0; gi < 2; ++gi) {
    int g = (c0 >> 2) + gi;
    float mean = sum1[vt * 32 + g] / N;
    float var = ss1[vt * 32 + g] / N - mean * mean;
    float r = rsqrtf(var + EPS);
    f32x4 v = gi ? v1 : v0;
#pragma unroll
    for (int j = 0; j < 4; ++j) {
      int c = g * 4 + j;
      float a = r * gs[c];
      float b = gb[c] - mean * a;
      o[gi * 4 + j] = (bf16_t)silu_f(v[j] * a + b);
    }
  }
  *(bf16x8*)(h1 + base) = o;
}

// ---------------- apply GN2 (affine inline) + SiLU in place ----------------
__global__ void apply_gn2(bf16_t* __restrict__ h,
                          const float* __restrict__ sum_c, const float* __restrict__ ss_c,
                          const float* __restrict__ gs, const float* __restrict__ gb) {
  size_t base = ((size_t)blockIdx.x * 256 + threadIdx.x) * 8;
  int vt = (int)(base / ((size_t)S_TOT * F_OUT));
  int c0 = (int)(base & (F_OUT - 1));
  int g = c0 >> 3;
  bf16x8 v = *(const bf16x8*)(h + base);
  float sg = 0.f, qg = 0.f;
#pragma unroll
  for (int j = 0; j < 8; ++j) {
    sg += sum_c[vt * 256 + g * 8 + j];
    qg += ss_c[vt * 256 + g * 8 + j];
  }
  float N = (float)(S_TOT * 8);
  float mean = sg / N;
  float var = qg / N - mean * mean;
  float r = rsqrtf(var + EPS);
  bf16x8 o;
#pragma unroll
  for (int j = 0; j < 8; ++j) {
    int c = g * 8 + j;
    float a = r * gs[c];
    float b = gb[c] - mean * a;
    o[j] = (bf16_t)silu_f((float)v[j] * a + b);
  }
  *(bf16x8*)(h + base) = o;
}

// ---------------- unified gather-conv GEMM v10 ----------------
// MEGA-TILE: block 192 rows x 256 cols, grid 256 = 1 block/CU.
// 4 waves, wave tile 192x64, acc[12][4] (192 VGPR). Per CU-substage the B
// stream is fetched ONCE (16KB) instead of 3x -> L1 ~440cyc << MFMA 768cyc.
// Per-wave MFMA burst per barrier = 48 MFMA (768cyc) -> fixed overhead ~28%.
// A: 3 gll16/wave (192 rows x 64B, XOR-swizzled gather source), ring-3
// (2 substages of flight ~2100cy covers HBM gather misses).
// B: 4 asm dwordx4 -> regs, double-buffered, 1 substage ahead (L2-hot).
// Uniform 7 VMEM/wave/substage -> steady s_waitcnt vmcnt(7).
template<int RE, int NSUB, bool XSK>
__global__ __launch_bounds__(256, 1) void conv_kernel(
    const bf16_t* __restrict__ hsrc, const bf16_t* __restrict__ Wp,
    const bf16_t* __restrict__ Wsp, const float* __restrict__ x,
    const int* __restrict__ adjc, const float* __restrict__ bias,
    const float* __restrict__ biask, bf16_t* __restrict__ outb,
    float* __restrict__ outf, float* __restrict__ sum_c, float* __restrict__ ss_c) {
  const int tid = threadIdx.x;
  const int wv = tid >> 6, l = tid & 63;
  const int lo = l & 15, hi = l >> 4;
  const int nw = wv;

  int swz = ((blockIdx.x & 7) << 5) + (blockIdx.x >> 3);   // bijective: 256 = 8*32
  int vt = swz >> 6;
  int rem = swz & 63;
  int s0 = rem * 192;

  __shared__ int adjs[1728];
  __shared__ bf16_t ab[3][6144];   // per buf: 192 rows x 32 elems (64B rows)

  for (int i = tid; i < 1728; i += 256) adjs[i] = adjc[s0 * 9 + i];
  __syncthreads();

  const bf16_t* hb = hsrc + (size_t)vt * ((size_t)S_TOT * RE);
  constexpr int NMAIN = XSK ? (NSUB - 4) : NSUB;

  // A-stage for substage s (tap=s%9, chunk=s/9): 3 gll16 per wave (48 rows).
  auto stageA = [&](int buf, int s) {
    int tap = s % 9, chunk = s / 9;
#pragma unroll
    for (int j2 = 0; j2 < 3; ++j2) {
      int row = wv * 48 + j2 * 16 + (l >> 2);
      int segs = (l & 3) ^ ((row >> 1) & 3);
      const bf16_t* g = hb + (size_t)adjs[row * 9 + tap] * RE + chunk * 32 + segs * 8;
      gll16(g, &ab[buf][(wv * 48 + j2 * 16) * 32]);
    }
  };

  // B-stage: 4 asm global loads into regs, wave's 64-col strip of kcg.
  auto asmB = [&](i32x4* dst, const bf16_t* wsrc, int kcg) {
    const bf16_t* p = wsrc + (size_t)kcg * 8192 + nw * 2048 + l * 8;
    asm volatile(
        "global_load_dwordx4 %0, %4, off\n\t"
        "global_load_dwordx4 %1, %4, off offset:1024\n\t"
        "global_load_dwordx4 %2, %4, off offset:2048\n\t"
        "global_load_dwordx4 %3, %4, off offset:3072"
        : "=&v"(dst[0]), "=&v"(dst[1]), "=&v"(dst[2]), "=&v"(dst[3])
        : "v"(p));
  };

  // x-skip stage: f32 -> bf16 reg path into same swizzled A layout (192 rows).
  auto stageX = [&](int buf, int sx) {
#pragma unroll
    for (int i = 0; i < 3; ++i) {
      int row = i * 64 + (tid >> 2);
      int q = tid & 3;
      const float* xr = x + ((size_t)vt * S_TOT + s0 + row) * F_IN + sx * 32 + q * 8;
      f32x4 xv0 = *(const f32x4*)(xr);
      f32x4 xv1 = *(const f32x4*)(xr + 4);
      bf16x8 w;
#pragma unroll
      for (int jj = 0; jj < 4; ++jj) {
        w[jj] = (bf16_t)xv0[jj];
        w[4 + jj] = (bf16_t)xv1[jj];
      }
      *(bf16x8*)(&ab[buf][row * 32 + ((q ^ ((row >> 1) & 3)) << 3)]) = w;
    }
  };

  f32x4 acc[12][4] = {};
  auto compute = [&](int buf, const i32x4* bv) {
    __builtin_amdgcn_s_setprio(1);
#pragma unroll
    for (int mi = 0; mi < 12; ++mi) {
      int rr = mi * 16 + lo;
      bf16x8 afr = *(const bf16x8*)(&ab[buf][rr * 32 + ((hi ^ ((rr >> 1) & 3)) << 3)]);
#pragma unroll
      for (int ni = 0; ni < 4; ++ni)
        acc[mi][ni] = __builtin_amdgcn_mfma_f32_16x16x32_bf16(
            afr, __builtin_bit_cast(bf16x8, bv[ni]), acc[mi][ni], 0, 0, 0);
    }
    __builtin_amdgcn_s_setprio(0);
  };

  i32x4 b0[4], b1[4];
  // Prologue: at body top in-flight = A(s)[3], B(s)[4], A(s+1)[3] = 10.
  stageA(0, 0);
  asmB(b0, Wp, 0);
  stageA(1, 1);
  int bcur3 = 0, bstg3 = 2;

  for (int s = 0; s < NMAIN - 2; s += 2) {
    // even body: use b0 (s), load b1 (s+1)
    asmB(b1, Wp, s + 1);                               // 14 in flight
    asm volatile("s_waitcnt vmcnt(7)" ::: "memory");   // drain A(s),B(s)
    __builtin_amdgcn_s_barrier();
    __builtin_amdgcn_sched_barrier(0);
    stageA(bstg3, s + 2);
    compute(bcur3, b0);
    bcur3 = (bcur3 == 2) ? 0 : bcur3 + 1;
    bstg3 = (bstg3 == 2) ? 0 : bstg3 + 1;
    // odd body: use b1 (s+1), load b0 (s+2)
    asmB(b0, Wp, s + 2);
    asm volatile("s_waitcnt vmcnt(7)" ::: "memory");
    __builtin_amdgcn_s_barrier();
    __builtin_amdgcn_sched_barrier(0);
    stageA(bstg3, s + 3);
    compute(bcur3, b1);
    bcur3 = (bcur3 == 2) ? 0 : bcur3 + 1;
    bstg3 = (bstg3 == 2) ? 0 : bstg3 + 1;
  }
  // body NMAIN-2: use b0, load last B into b1; no more stageA
  asmB(b1, Wp, NMAIN - 1);
  asm volatile("s_waitcnt vmcnt(7)" ::: "memory");
  __builtin_amdgcn_s_barrier();
  __builtin_amdgcn_sched_barrier(0);
  compute(bcur3, b0);
  bcur3 = (bcur3 == 2) ? 0 : bcur3 + 1;
  // body NMAIN-1: use b1
  asm volatile("s_waitcnt vmcnt(0)" ::: "memory");
  __builtin_amdgcn_s_barrier();
  __builtin_amdgcn_sched_barrier(0);
  compute(bcur3, b1);

  // ---- x-skip tail: 4 K32 substages from f32 x with W_skip ----
  if (XSK) {
#pragma unroll
    for (int sx = 0; sx < 4; ++sx) {
      int tb = sx & 1;
      __syncthreads();
      stageX(tb, sx);
      if (sx & 1) asmB(b1, Wsp, sx); else asmB(b0, Wsp, sx);
      asm volatile("s_waitcnt vmcnt(0)" ::: "memory");
      __syncthreads();
      __builtin_amdgcn_sched_barrier(0);
      compute(tb, (sx & 1) ? (const i32x4*)b1 : (const i32x4*)b0);
    }
  }

  if (!XSK) {
    bf16_t* ob = outb + ((size_t)vt * S_TOT + s0) * 256;
#pragma unroll
    for (int ni = 0; ni < 4; ++ni) {
      int o = nw * 64 + ni * 16 + lo;
      float bv = bias[o];
      float s_ = 0.f, q_ = 0.f;
#pragma unroll
      for (int mi = 0; mi < 12; ++mi)
#pragma unroll
        for (int r2 = 0; r2 < 4; ++r2) {
          int srow = mi * 16 + hi * 4 + r2;
          float v = acc[mi][ni][r2] + bv;
          ob[(size_t)srow * 256 + o] = (bf16_t)v;
          s_ += v; q_ += v * v;
        }
      s_ += __shfl_xor(s_, 16); s_ += __shfl_xor(s_, 32);
      q_ += __shfl_xor(q_, 16); q_ += __shfl_xor(q_, 32);
      if (hi == 0) {
        atomicAdd(&sum_c[vt * 256 + o], s_);
        atomicAdd(&ss_c[vt * 256 + o], q_);
      }
    }
  } else {
    float* of = outf + ((size_t)vt * S_TOT + s0) * 256;
#pragma unroll
    for (int ni = 0; ni < 4; ++ni) {
      int o = nw * 64 + ni * 16 + lo;
      float bv = bias[o] + biask[o];
#pragma unroll
      for (int mi = 0; mi < 12; ++mi)
#pragma unroll
        for (int r2 = 0; r2 < 4; ++r2) {
          int srow = mi * 16 + hi * 4 + r2;
          of[(size_t)srow * 256 + o] = acc[mi][ni][r2] + bv;
        }
    }
  }
}

extern "C" void kernel_launch(void* const* d_in, const int* in_sizes, int n_in,
                              void* d_out, int out_size, void* d_ws, size_t ws_size,
                              hipStream_t stream) {
  const float* x      = (const float*)d_in[0];
  const int*   adjc   = (const int*)d_in[1];
  const float* gn1_s  = (const float*)d_in[2];
  const float* gn1_b  = (const float*)d_in[3];
  const float* gn2_s  = (const float*)d_in[4];
  const float* gn2_b  = (const float*)d_in[5];
  const float* W_skip = (const float*)d_in[6];
  const float* b_skip = (const float*)d_in[7];
  const float* W1     = (const float*)d_in[8];
  const float* b1     = (const float*)d_in[9];
  const float* W2     = (const float*)d_in[10];
  const float* b2     = (const float*)d_in[11];
  float* out = (float*)d_out;

  float* sum1  = (float*)d_ws;           // 128
  float* ss1   = sum1 + 128;             // 128
  float* sum_c = ss1 + 128;              // 1024
  float* ss_c  = sum_c + 1024;           // 1024
  float* pad   = ss_c + 1024;            // 3072 (layout pad)
  bf16_t* W1p  = (bf16_t*)(pad + 3072);  // 294912
  bf16_t* W2p  = W1p + 294912;           // 589824
  bf16_t* Wsp  = W2p + 589824;           // 32768
  bf16_t* h1   = Wsp + 32768;            // 6291456
  bf16_t* out1 = h1 + 6291456;           // 12582912 (reused in place as h2)

  hipMemsetAsync(sum1, 0, (128 + 128 + 1024 + 1024) * sizeof(float), stream);
  prep_kernel<<<640, 256, 0, stream>>>(W1, W2, W_skip, W1p, W2p, Wsp, x, sum1, ss1);
  apply_gn1<<<3072, 256, 0, stream>>>(x, sum1, ss1, gn1_s, gn1_b, h1);
  conv_kernel<128, 36, false><<<256, 256, 0, stream>>>(
      h1, W1p, nullptr, nullptr, adjc, b1, nullptr, out1, nullptr, sum_c, ss_c);
  apply_gn2<<<6144, 256, 0, stream>>>(out1, sum_c, ss_c, gn2_s, gn2_b);
  conv_kernel<256, 76, true><<<256, 256, 0, stream>>>(
      out1, W2p, Wsp, x, adjc, b2, b_skip, nullptr, out, nullptr, nullptr);
}

// Round 11
// 158.888 us; speedup vs baseline: 1.1314x; 1.1314x over previous
//
#include <hip/hip_runtime.h>
#include <hip/hip_bf16.h>

typedef __bf16 bf16_t;
typedef __bf16 bf16x8 __attribute__((ext_vector_type(8)));
typedef float f32x4 __attribute__((ext_vector_type(4)));
typedef int i32x4 __attribute__((ext_vector_type(4)));

#define S_TOT 12288
#define F_IN 128
#define F_OUT 256
#define EPS 1e-5f

static __device__ __forceinline__ float silu_f(float v) {
  return v / (1.0f + __expf(-v));
}

static __device__ __forceinline__ void gll16(const bf16_t* g, bf16_t* l) {
  __builtin_amdgcn_global_load_lds(
      (const __attribute__((address_space(1))) void*)(const void*)g,
      (__attribute__((address_space(3))) void*)(void*)l, 16, 0, 0);
}

// ---------------- prep: pack weights (blocks 0..447) + GN1 stats (448..639) ----
// CHUNK-MAJOR pack: kcg = chunk*9 + tap. Unit (kcg, cb): lane l holds
// B[f=32*chunk+8*(l>>4)+j of W_tap][o=16cb+(l&15)] at unit*1024B + l*16B.
__global__ void prep_kernel(const float* __restrict__ W1,
                            const float* __restrict__ W2,
                            const float* __restrict__ Wsk,
                            bf16_t* __restrict__ W1p,
                            bf16_t* __restrict__ W2p,
                            bf16_t* __restrict__ Wsp,
                            const float* __restrict__ x,
                            float* __restrict__ sum1, float* __restrict__ ss1) {
  __shared__ float gs[32], gq[32];
  if (blockIdx.x < 448) {
    int w = blockIdx.x * 4 + (threadIdx.x >> 6);
    int l = threadIdx.x & 63;
    int lo = l & 15, hi = l >> 4;
    const float* src;
    bf16_t* dst;
    int fbase, obase;
    if (w < 576) {
      int kcg = w >> 4, cb = w & 15;
      int tap = kcg % 9, chunk = kcg / 9;
      src = W1 + tap * 32768;
      dst = W1p + (size_t)w * 512;
      fbase = 32 * chunk + 8 * hi; obase = 16 * cb + lo;
    } else if (w < 1728) {
      int idx = w - 576;
      int kcg = idx >> 4, cb = idx & 15;
      int tap = kcg % 9, chunk = kcg / 9;
      src = W2 + tap * 65536;
      dst = W2p + (size_t)idx * 512;
      fbase = 32 * chunk + 8 * hi; obase = 16 * cb + lo;
    } else {
      int idx = w - 1728;
      int kc = idx >> 4, cb = idx & 15;
      src = Wsk;
      dst = Wsp + (size_t)idx * 512;
      fbase = 32 * kc + 8 * hi; obase = 16 * cb + lo;
    }
    bf16x8 v;
#pragma unroll
    for (int j = 0; j < 8; ++j)
      v[j] = (bf16_t)src[(fbase + j) * 256 + obase];
    *(bf16x8*)(dst + l * 8) = v;
  } else {
    int blk = blockIdx.x - 448;
    int vt = blk & 3;
    int s0 = (blk >> 2) * 256;
    int t = threadIdx.x;
    int col = t & 31, ro = t >> 5;
    float s_ = 0.f, q_ = 0.f;
    const f32x4* xp = (const f32x4*)(x + ((size_t)vt * S_TOT + s0) * F_IN);
#pragma unroll 4
    for (int it = 0; it < 32; ++it) {
      f32x4 v = xp[(size_t)(it * 8 + ro) * 32 + col];
      s_ += v[0] + v[1] + v[2] + v[3];
      q_ += v[0]*v[0] + v[1]*v[1] + v[2]*v[2] + v[3]*v[3];
    }
    if (t < 32) { gs[t] = 0.f; gq[t] = 0.f; }
    __syncthreads();
    atomicAdd(&gs[col], s_);
    atomicAdd(&gq[col], q_);
    __syncthreads();
    if (t < 32) {
      atomicAdd(&sum1[vt * 32 + t], gs[t]);
      atomicAdd(&ss1[vt * 32 + t], gq[t]);
    }
  }
}

// ---------------- apply GN1 (affine inline) + SiLU -> h1 ----------------
__global__ void apply_gn1(const float* __restrict__ x,
                          const float* __restrict__ sum1, const float* __restrict__ ss1,
                          const float* __restrict__ gs, const float* __restrict__ gb,
                          bf16_t* __restrict__ h1) {
  size_t base = ((size_t)blockIdx.x * 256 + threadIdx.x) * 8;
  int vt = (int)(base / ((size_t)S_TOT * F_IN));
  int c0 = (int)(base & (F_IN - 1));
  const f32x4* xp = (const f32x4*)(x + base);
  f32x4 v0 = xp[0], v1 = xp[1];
  float N = (float)(S_TOT * 4);
  bf16x8 o;
#pragma unroll
  for (int gi = 0; gi < 2; ++gi) {
    int g = (c0 >> 2) + gi;
    float mean = sum1[vt * 32 + g] / N;
    float var = ss1[vt * 32 + g] / N - mean * mean;
    float r = rsqrtf(var + EPS);
    f32x4 v = gi ? v1 : v0;
#pragma unroll
    for (int j = 0; j < 4; ++j) {
      int c = g * 4 + j;
      float a = r * gs[c];
      float b = gb[c] - mean * a;
      o[gi * 4 + j] = (bf16_t)silu_f(v[j] * a + b);
    }
  }
  *(bf16x8*)(h1 + base) = o;
}

// ---------------- apply GN2 (affine inline) + SiLU in place ----------------
__global__ void apply_gn2(bf16_t* __restrict__ h,
                          const float* __restrict__ sum_c, const float* __restrict__ ss_c,
                          const float* __restrict__ gs, const float* __restrict__ gb) {
  size_t base = ((size_t)blockIdx.x * 256 + threadIdx.x) * 8;
  int vt = (int)(base / ((size_t)S_TOT * F_OUT));
  int c0 = (int)(base & (F_OUT - 1));
  int g = c0 >> 3;
  bf16x8 v = *(const bf16x8*)(h + base);
  float sg = 0.f, qg = 0.f;
#pragma unroll
  for (int j = 0; j < 8; ++j) {
    sg += sum_c[vt * 256 + g * 8 + j];
    qg += ss_c[vt * 256 + g * 8 + j];
  }
  float N = (float)(S_TOT * 8);
  float mean = sg / N;
  float var = qg / N - mean * mean;
  float r = rsqrtf(var + EPS);
  bf16x8 o;
#pragma unroll
  for (int j = 0; j < 8; ++j) {
    int c = g * 8 + j;
    float a = r * gs[c];
    float b = gb[c] - mean * a;
    o[j] = (bf16_t)silu_f((float)v[j] * a + b);
  }
  *(bf16x8*)(h + base) = o;
}

// ---------------- unified gather-conv GEMM v11 ----------------
// Block 192 rows x 256 cols, 512 threads = 8 waves, wave grid 2x4
// (rh = row half 96 rows, cq = col quarter 64 cols), acc[6][4] (96 VGPR).
// Grid 256 = 1 block/CU -> 2 waves/SIMD (TLP that R10 lacked) with the
// minimal-traffic C=1 profile: per CU-substage B-L1 32KB, A-LDS-read 48KB,
// LDS-write 12KB, L1 44KB -> MFMA (931cy) is the max pipe.
// A: 192x64B via 12 real gll16 (waves 0-3: 2 each; 4-7: 1 real + 1 scratch pad
// for uniform vmcnt). B: 4 asm dwordx4 -> regs, dbuf. Steady vmcnt(6).
template<int RE, int NSUB, bool XSK>
__global__ __launch_bounds__(512, 2) void conv_kernel(
    const bf16_t* __restrict__ hsrc, const bf16_t* __restrict__ Wp,
    const bf16_t* __restrict__ Wsp, const float* __restrict__ x,
    const int* __restrict__ adjc, const float* __restrict__ bias,
    const float* __restrict__ biask, bf16_t* __restrict__ outb,
    float* __restrict__ outf, float* __restrict__ sum_c, float* __restrict__ ss_c) {
  const int tid = threadIdx.x;
  const int wv = tid >> 6, l = tid & 63;
  const int lo = l & 15, hi = l >> 4;
  const int rh = wv >> 2, cq = wv & 3;

  int swz = ((blockIdx.x & 7) << 5) + (blockIdx.x >> 3);   // bijective: 256 = 8*32
  int vt = swz >> 6;
  int rem = swz & 63;
  int s0 = rem * 192;

  __shared__ int adjs[1728];
  __shared__ bf16_t ab[3][6144];      // per buf: 192 rows x 32 elems (64B rows)
  __shared__ bf16_t scratch[512];     // dummy gll sink (waves 4-7)

  for (int i = tid; i < 1728; i += 512) adjs[i] = adjc[s0 * 9 + i];
  __syncthreads();

  const bf16_t* hb = hsrc + (size_t)vt * ((size_t)S_TOT * RE);
  constexpr int NMAIN = XSK ? (NSUB - 4) : NSUB;

  // A-stage (tap=s%9, chunk=s/9): 12 real gll16 over 16-row groups, 2/wave.
  auto stageA = [&](int buf, int s) {
    int tap = s % 9, chunk = s / 9;
    {
      int g = wv;
      int row = g * 16 + (l >> 2);
      int segs = (l & 3) ^ ((row >> 1) & 3);
      const bf16_t* gp = hb + (size_t)adjs[row * 9 + tap] * RE + chunk * 32 + segs * 8;
      gll16(gp, &ab[buf][g * 512]);
    }
    if (wv < 4) {
      int g = 8 + wv;
      int row = g * 16 + (l >> 2);
      int segs = (l & 3) ^ ((row >> 1) & 3);
      const bf16_t* gp = hb + (size_t)adjs[row * 9 + tap] * RE + chunk * 32 + segs * 8;
      gll16(gp, &ab[buf][g * 512]);
    } else {
      gll16(Wp + l * 8, scratch);     // pad: uniform vmcnt, garbage sink
    }
  };

  // B-stage: 4 asm global loads into regs, this wave's 64-col strip (cq).
  auto asmB = [&](i32x4* dst, const bf16_t* wsrc, int kcg) {
    const bf16_t* p = wsrc + (size_t)kcg * 8192 + cq * 2048 + l * 8;
    asm volatile(
        "global_load_dwordx4 %0, %4, off\n\t"
        "global_load_dwordx4 %1, %4, off offset:1024\n\t"
        "global_load_dwordx4 %2, %4, off offset:2048\n\t"
        "global_load_dwordx4 %3, %4, off offset:3072"
        : "=&v"(dst[0]), "=&v"(dst[1]), "=&v"(dst[2]), "=&v"(dst[3])
        : "v"(p));
  };

  // x-skip stage: f32 -> bf16 reg path into same swizzled A layout (192 rows).
  auto stageX = [&](int buf, int sx) {
#pragma unroll
    for (int i = 0; i < 2; ++i) {
      int idx = i * 512 + tid;
      if (idx < 768) {
        int row = idx >> 2, q = idx & 3;
        const float* xr = x + ((size_t)vt * S_TOT + s0 + row) * F_IN + sx * 32 + q * 8;
        f32x4 xv0 = *(const f32x4*)(xr);
        f32x4 xv1 = *(const f32x4*)(xr + 4);
        bf16x8 w;
#pragma unroll
        for (int jj = 0; jj < 4; ++jj) {
          w[jj] = (bf16_t)xv0[jj];
          w[4 + jj] = (bf16_t)xv1[jj];
        }
        *(bf16x8*)(&ab[buf][row * 32 + ((q ^ ((row >> 1) & 3)) << 3)]) = w;
      }
    }
  };

  f32x4 acc[6][4] = {};
  auto compute = [&](int buf, const i32x4* bv) {
    __builtin_amdgcn_s_setprio(1);
#pragma unroll
    for (int mi = 0; mi < 6; ++mi) {
      int rr = rh * 96 + mi * 16 + lo;
      bf16x8 afr = *(const bf16x8*)(&ab[buf][rr * 32 + ((hi ^ ((rr >> 1) & 3)) << 3)]);
#pragma unroll
      for (int ni = 0; ni < 4; ++ni)
        acc[mi][ni] = __builtin_amdgcn_mfma_f32_16x16x32_bf16(
            afr, __builtin_bit_cast(bf16x8, bv[ni]), acc[mi][ni], 0, 0, 0);
    }
    __builtin_amdgcn_s_setprio(0);
  };

  i32x4 b0[4], b1[4];
  // Prologue: top-of-body invariant = A(s)[2], B(s)[4], A(s+1)[2] = 8 in flight.
  stageA(0, 0);
  asmB(b0, Wp, 0);
  stageA(1, 1);
  int bcur3 = 0, bstg3 = 2;

  for (int s = 0; s < NMAIN - 2; s += 2) {
    // even body: use b0 (s), load b1 (s+1)
    asmB(b1, Wp, s + 1);                               // 12 in flight
    asm volatile("s_waitcnt vmcnt(6)" ::: "memory");   // drain A(s), B(s)
    __builtin_amdgcn_s_barrier();
    __builtin_amdgcn_sched_barrier(0);
    stageA(bstg3, s + 2);
    compute(bcur3, b0);
    bcur3 = (bcur3 == 2) ? 0 : bcur3 + 1;
    bstg3 = (bstg3 == 2) ? 0 : bstg3 + 1;
    // odd body: use b1 (s+1), load b0 (s+2)
    asmB(b0, Wp, s + 2);
    asm volatile("s_waitcnt vmcnt(6)" ::: "memory");
    __builtin_amdgcn_s_barrier();
    __builtin_amdgcn_sched_barrier(0);
    stageA(bstg3, s + 3);
    compute(bcur3, b1);
    bcur3 = (bcur3 == 2) ? 0 : bcur3 + 1;
    bstg3 = (bstg3 == 2) ? 0 : bstg3 + 1;
  }
  // body NMAIN-2: use b0, load last B into b1; no more stageA
  asmB(b1, Wp, NMAIN - 1);
  asm volatile("s_waitcnt vmcnt(6)" ::: "memory");
  __builtin_amdgcn_s_barrier();
  __builtin_amdgcn_sched_barrier(0);
  compute(bcur3, b0);
  bcur3 = (bcur3 == 2) ? 0 : bcur3 + 1;
  // body NMAIN-1: use b1
  asm volatile("s_waitcnt vmcnt(0)" ::: "memory");
  __builtin_amdgcn_s_barrier();
  __builtin_amdgcn_sched_barrier(0);
  compute(bcur3, b1);

  // ---- x-skip tail: 4 K32 substages from f32 x with W_skip ----
  if (XSK) {
#pragma unroll
    for (int sx = 0; sx < 4; ++sx) {
      int tb = sx & 1;
      __syncthreads();
      stageX(tb, sx);
      if (sx & 1) asmB(b1, Wsp, sx); else asmB(b0, Wsp, sx);
      asm volatile("s_waitcnt vmcnt(0)" ::: "memory");
      __syncthreads();
      __builtin_amdgcn_sched_barrier(0);
      compute(tb, (sx & 1) ? (const i32x4*)b1 : (const i32x4*)b0);
    }
  }

  if (!XSK) {
    bf16_t* ob = outb + ((size_t)vt * S_TOT + s0) * 256;
#pragma unroll
    for (int ni = 0; ni < 4; ++ni) {
      int o = cq * 64 + ni * 16 + lo;
      float bv = bias[o];
      float s_ = 0.f, q_ = 0.f;
#pragma unroll
      for (int mi = 0; mi < 6; ++mi)
#pragma unroll
        for (int r2 = 0; r2 < 4; ++r2) {
          int srow = rh * 96 + mi * 16 + hi * 4 + r2;
          float v = acc[mi][ni][r2] + bv;
          ob[(size_t)srow * 256 + o] = (bf16_t)v;
          s_ += v; q_ += v * v;
        }
      s_ += __shfl_xor(s_, 16); s_ += __shfl_xor(s_, 32);
      q_ += __shfl_xor(q_, 16); q_ += __shfl_xor(q_, 32);
      if (hi == 0) {
        atomicAdd(&sum_c[vt * 256 + o], s_);
        atomicAdd(&ss_c[vt * 256 + o], q_);
      }
    }
  } else {
    float* of = outf + ((size_t)vt * S_TOT + s0) * 256;
#pragma unroll
    for (int ni = 0; ni < 4; ++ni) {
      int o = cq * 64 + ni * 16 + lo;
      float bv = bias[o] + biask[o];
#pragma unroll
      for (int mi = 0; mi < 6; ++mi)
#pragma unroll
        for (int r2 = 0; r2 < 4; ++r2) {
          int srow = rh * 96 + mi * 16 + hi * 4 + r2;
          of[(size_t)srow * 256 + o] = acc[mi][ni][r2] + bv;
        }
    }
  }
}

extern "C" void kernel_launch(void* const* d_in, const int* in_sizes, int n_in,
                              void* d_out, int out_size, void* d_ws, size_t ws_size,
                              hipStream_t stream) {
  const float* x      = (const float*)d_in[0];
  const int*   adjc   = (const int*)d_in[1];
  const float* gn1_s  = (const float*)d_in[2];
  const float* gn1_b  = (const float*)d_in[3];
  const float* gn2_s  = (const float*)d_in[4];
  const float* gn2_b  = (const float*)d_in[5];
  const float* W_skip = (const float*)d_in[6];
  const float* b_skip = (const float*)d_in[7];
  const float* W1     = (const float*)d_in[8];
  const float* b1     = (const float*)d_in[9];
  const float* W2     = (const float*)d_in[10];
  const float* b2     = (const float*)d_in[11];
  float* out = (float*)d_out;

  float* sum1  = (float*)d_ws;           // 128
  float* ss1   = sum1 + 128;             // 128
  float* sum_c = ss1 + 128;              // 1024
  float* ss_c  = sum_c + 1024;           // 1024
  float* pad   = ss_c + 1024;            // 3072 (layout pad)
  bf16_t* W1p  = (bf16_t*)(pad + 3072);  // 294912
  bf16_t* W2p  = W1p + 294912;           // 589824
  bf16_t* Wsp  = W2p + 589824;           // 32768
  bf16_t* h1   = Wsp + 32768;            // 6291456
  bf16_t* out1 = h1 + 6291456;           // 12582912 (reused in place as h2)

  hipMemsetAsync(sum1, 0, (128 + 128 + 1024 + 1024) * sizeof(float), stream);
  prep_kernel<<<640, 256, 0, stream>>>(W1, W2, W_skip, W1p, W2p, Wsp, x, sum1, ss1);
  apply_gn1<<<3072, 256, 0, stream>>>(x, sum1, ss1, gn1_s, gn1_b, h1);
  conv_kernel<128, 36, false><<<256, 512, 0, stream>>>(
      h1, W1p, nullptr, nullptr, adjc, b1, nullptr, out1, nullptr, sum_c, ss_c);
  apply_gn2<<<6144, 256, 0, stream>>>(out1, sum_c, ss_c, gn2_s, gn2_b);
  conv_kernel<256, 76, true><<<256, 512, 0, stream>>>(
      out1, W2p, Wsp, x, adjc, b2, b_skip, nullptr, out, nullptr, nullptr);
}

// Round 12
// 137.501 us; speedup vs baseline: 1.3074x; 1.1555x over previous
//
#include <hip/hip_runtime.h>
#include <hip/hip_bf16.h>

typedef __bf16 bf16_t;
typedef __bf16 bf16x8 __attribute__((ext_vector_type(8)));
typedef float f32x4 __attribute__((ext_vector_type(4)));
typedef int i32x4 __attribute__((ext_vector_type(4)));

#define S_TOT 12288
#define F_IN 128
#define F_OUT 256
#define EPS 1e-5f

static __device__ __forceinline__ float silu_f(float v) {
  return v / (1.0f + __expf(-v));
}

static __device__ __forceinline__ void gll16(const bf16_t* g, bf16_t* l) {
  __builtin_amdgcn_global_load_lds(
      (const __attribute__((address_space(1))) void*)(const void*)g,
      (__attribute__((address_space(3))) void*)(void*)l, 16, 0, 0);
}

// ---------------- prep: pack weights (blocks 0..447) + GN1 stats (448..639) ----
// CHUNK-MAJOR pack: kcg = chunk*9 + tap. Unit (kcg, cb): lane l holds
// B[f=32*chunk+8*(l>>4)+j of W_tap][o=16cb+(l&15)] at unit*1024B + l*16B.
__global__ void prep_kernel(const float* __restrict__ W1,
                            const float* __restrict__ W2,
                            const float* __restrict__ Wsk,
                            bf16_t* __restrict__ W1p,
                            bf16_t* __restrict__ W2p,
                            bf16_t* __restrict__ Wsp,
                            const float* __restrict__ x,
                            float* __restrict__ sum1, float* __restrict__ ss1) {
  __shared__ float gs[32], gq[32];
  if (blockIdx.x < 448) {
    int w = blockIdx.x * 4 + (threadIdx.x >> 6);
    int l = threadIdx.x & 63;
    int lo = l & 15, hi = l >> 4;
    const float* src;
    bf16_t* dst;
    int fbase, obase;
    if (w < 576) {
      int kcg = w >> 4, cb = w & 15;
      int tap = kcg % 9, chunk = kcg / 9;
      src = W1 + tap * 32768;
      dst = W1p + (size_t)w * 512;
      fbase = 32 * chunk + 8 * hi; obase = 16 * cb + lo;
    } else if (w < 1728) {
      int idx = w - 576;
      int kcg = idx >> 4, cb = idx & 15;
      int tap = kcg % 9, chunk = kcg / 9;
      src = W2 + tap * 65536;
      dst = W2p + (size_t)idx * 512;
      fbase = 32 * chunk + 8 * hi; obase = 16 * cb + lo;
    } else {
      int idx = w - 1728;
      int kc = idx >> 4, cb = idx & 15;
      src = Wsk;
      dst = Wsp + (size_t)idx * 512;
      fbase = 32 * kc + 8 * hi; obase = 16 * cb + lo;
    }
    bf16x8 v;
#pragma unroll
    for (int j = 0; j < 8; ++j)
      v[j] = (bf16_t)src[(fbase + j) * 256 + obase];
    *(bf16x8*)(dst + l * 8) = v;
  } else {
    int blk = blockIdx.x - 448;
    int vt = blk & 3;
    int s0 = (blk >> 2) * 256;
    int t = threadIdx.x;
    int col = t & 31, ro = t >> 5;
    float s_ = 0.f, q_ = 0.f;
    const f32x4* xp = (const f32x4*)(x + ((size_t)vt * S_TOT + s0) * F_IN);
#pragma unroll 4
    for (int it = 0; it < 32; ++it) {
      f32x4 v = xp[(size_t)(it * 8 + ro) * 32 + col];
      s_ += v[0] + v[1] + v[2] + v[3];
      q_ += v[0]*v[0] + v[1]*v[1] + v[2]*v[2] + v[3]*v[3];
    }
    if (t < 32) { gs[t] = 0.f; gq[t] = 0.f; }
    __syncthreads();
    atomicAdd(&gs[col], s_);
    atomicAdd(&gq[col], q_);
    __syncthreads();
    if (t < 32) {
      atomicAdd(&sum1[vt * 32 + t], gs[t]);
      atomicAdd(&ss1[vt * 32 + t], gq[t]);
    }
  }
}

// ---------------- apply GN1 (affine inline) + SiLU -> h1 ----------------
__global__ void apply_gn1(const float* __restrict__ x,
                          const float* __restrict__ sum1, const float* __restrict__ ss1,
                          const float* __restrict__ gs, const float* __restrict__ gb,
                          bf16_t* __restrict__ h1) {
  size_t base = ((size_t)blockIdx.x * 256 + threadIdx.x) * 8;
  int vt = (int)(base / ((size_t)S_TOT * F_IN));
  int c0 = (int)(base & (F_IN - 1));
  const f32x4* xp = (const f32x4*)(x + base);
  f32x4 v0 = xp[0], v1 = xp[1];
  float N = (float)(S_TOT * 4);
  bf16x8 o;
#pragma unroll
  for (int gi = 0; gi < 2; ++gi) {
    int g = (c0 >> 2) + gi;
    float mean = sum1[vt * 32 + g] / N;
    float var = ss1[vt * 32 + g] / N - mean * mean;
    float r = rsqrtf(var + EPS);
    f32x4 v = gi ? v1 : v0;
#pragma unroll
    for (int j = 0; j < 4; ++j) {
      int c = g * 4 + j;
      float a = r * gs[c];
      float b = gb[c] - mean * a;
      o[gi * 4 + j] = (bf16_t)silu_f(v[j] * a + b);
    }
  }
  *(bf16x8*)(h1 + base) = o;
}

// ---------------- apply GN2 (affine inline) + SiLU in place ----------------
__global__ void apply_gn2(bf16_t* __restrict__ h,
                          const float* __restrict__ sum_c, const float* __restrict__ ss_c,
                          const float* __restrict__ gs, const float* __restrict__ gb) {
  size_t base = ((size_t)blockIdx.x * 256 + threadIdx.x) * 8;
  int vt = (int)(base / ((size_t)S_TOT * F_OUT));
  int c0 = (int)(base & (F_OUT - 1));
  int g = c0 >> 3;
  bf16x8 v = *(const bf16x8*)(h + base);
  float sg = 0.f, qg = 0.f;
#pragma unroll
  for (int j = 0; j < 8; ++j) {
    sg += sum_c[vt * 256 + g * 8 + j];
    qg += ss_c[vt * 256 + g * 8 + j];
  }
  float N = (float)(S_TOT * 8);
  float mean = sg / N;
  float var = qg / N - mean * mean;
  float r = rsqrtf(var + EPS);
  bf16x8 o;
#pragma unroll
  for (int j = 0; j < 8; ++j) {
    int c = g * 8 + j;
    float a = r * gs[c];
    float b = gb[c] - mean * a;
    o[j] = (bf16_t)silu_f((float)v[j] * a + b);
  }
  *(bf16x8*)(h + base) = o;
}

// ---------------- unified gather-conv GEMM v12 ----------------
// = R8 config (64 rows x 256 cols, 4 waves 64x64, grid 768 = 3 blocks/CU)
// + K64 PER BARRIER: each iteration covers a chunk PAIR (2c,2c+1) of one tap.
// Per iteration: 32 MFMA (620cy) against the same fixed overhead (~350cy of
// vmcnt+barrier+ds_read latency) that R8 paid per 16 MFMA -> amortized 2x.
// A: 2 gll16/wave into ab[buf][2][64x32] (pair is 128B-contiguous in source).
// B: 8 asm dwordx4 (chunk pair = kcg, kcg+9 in existing pack; no repack).
// Uniform 10 VMEM/wave/iter -> steady vmcnt(10); A 2 iters in flight, B 1.
template<int RE, int NM64, bool XSK>
__global__ __launch_bounds__(256, 3) void conv_kernel(
    const bf16_t* __restrict__ hsrc, const bf16_t* __restrict__ Wp,
    const bf16_t* __restrict__ Wsp, const float* __restrict__ x,
    const int* __restrict__ adjc, const float* __restrict__ bias,
    const float* __restrict__ biask, bf16_t* __restrict__ outb,
    float* __restrict__ outf, float* __restrict__ sum_c, float* __restrict__ ss_c) {
  const int tid = threadIdx.x;
  const int wv = tid >> 6, l = tid & 63;
  const int lo = l & 15, hi = l >> 4;
  const int nw = wv;

  int swz = ((blockIdx.x & 7) * 96) + (blockIdx.x >> 3);   // bijective: 768 = 8*96
  int vt = swz / 192;
  int rem = swz - vt * 192;
  int s0 = rem * 64;

  __shared__ int adjs[576];
  __shared__ bf16_t ab[3][2][2048];   // ring-3, 2 chunks, 64 rows x 32 (64B rows)

  for (int i = tid; i < 576; i += 256) adjs[i] = adjc[s0 * 9 + i];
  __syncthreads();

  const bf16_t* hb = hsrc + (size_t)vt * ((size_t)S_TOT * RE);

  // A-stage for K64 iteration i (tap=i%9, cpair=i/9): 2 gll16 per wave.
  auto stageA = [&](int buf, int i) {
    int tap = i % 9, cpair = i / 9;
    int row = wv * 16 + (l >> 2);
    int segs = (l & 3) ^ ((row >> 1) & 3);
    const bf16_t* g = hb + (size_t)adjs[row * 9 + tap] * RE + cpair * 64 + segs * 8;
    gll16(g, &ab[buf][0][wv * 512]);
    gll16(g + 32, &ab[buf][1][wv * 512]);
  };

  // B-stage: 8 asm dwordx4 into regs; chunk pair = units kcg, kcg+9.
  auto asmB = [&](i32x4* dst, int i) {
    int tap = i % 9, cpair = i / 9;
    const bf16_t* pa = Wp + (size_t)(18 * cpair + tap) * 8192 + nw * 2048 + l * 8;
    const bf16_t* pb = pa + 9 * 8192;
    asm volatile(
        "global_load_dwordx4 %0, %4, off\n\t"
        "global_load_dwordx4 %1, %4, off offset:1024\n\t"
        "global_load_dwordx4 %2, %4, off offset:2048\n\t"
        "global_load_dwordx4 %3, %4, off offset:3072"
        : "=&v"(dst[0]), "=&v"(dst[1]), "=&v"(dst[2]), "=&v"(dst[3])
        : "v"(pa));
    asm volatile(
        "global_load_dwordx4 %0, %4, off\n\t"
        "global_load_dwordx4 %1, %4, off offset:1024\n\t"
        "global_load_dwordx4 %2, %4, off offset:2048\n\t"
        "global_load_dwordx4 %3, %4, off offset:3072"
        : "=&v"(dst[4]), "=&v"(dst[5]), "=&v"(dst[6]), "=&v"(dst[7])
        : "v"(pb));
  };

  // x-skip B: chunk pair 2sx, 2sx+1 of Wsp (adjacent units).
  auto asmBx = [&](i32x4* dst, int sx) {
    const bf16_t* pa = Wsp + (size_t)(2 * sx) * 8192 + nw * 2048 + l * 8;
    const bf16_t* pb = pa + 8192;
    asm volatile(
        "global_load_dwordx4 %0, %4, off\n\t"
        "global_load_dwordx4 %1, %4, off offset:1024\n\t"
        "global_load_dwordx4 %2, %4, off offset:2048\n\t"
        "global_load_dwordx4 %3, %4, off offset:3072"
        : "=&v"(dst[0]), "=&v"(dst[1]), "=&v"(dst[2]), "=&v"(dst[3])
        : "v"(pa));
    asm volatile(
        "global_load_dwordx4 %0, %4, off\n\t"
        "global_load_dwordx4 %1, %4, off offset:1024\n\t"
        "global_load_dwordx4 %2, %4, off offset:2048\n\t"
        "global_load_dwordx4 %3, %4, off offset:3072"
        : "=&v"(dst[4]), "=&v"(dst[5]), "=&v"(dst[6]), "=&v"(dst[7])
        : "v"(pb));
  };

  // x-skip stage: f32 -> bf16 reg path, both chunks of 64-elem slice sx.
  auto stageX = [&](int buf, int sx) {
    int row = tid >> 2, q = tid & 3;
    const float* xr = x + ((size_t)vt * S_TOT + s0 + row) * F_IN + sx * 64 + q * 8;
#pragma unroll
    for (int sc = 0; sc < 2; ++sc) {
      f32x4 xv0 = *(const f32x4*)(xr + sc * 32);
      f32x4 xv1 = *(const f32x4*)(xr + sc * 32 + 4);
      bf16x8 w;
#pragma unroll
      for (int jj = 0; jj < 4; ++jj) {
        w[jj] = (bf16_t)xv0[jj];
        w[4 + jj] = (bf16_t)xv1[jj];
      }
      *(bf16x8*)(&ab[buf][sc][row * 32 + ((q ^ ((row >> 1) & 3)) << 3)]) = w;
    }
  };

  f32x4 acc[4][4] = {};
  auto compute = [&](int buf, const i32x4* bv) {
    __builtin_amdgcn_s_setprio(1);
#pragma unroll
    for (int sc = 0; sc < 2; ++sc) {
      bf16x8 afr[4];
#pragma unroll
      for (int mi = 0; mi < 4; ++mi) {
        int rr = mi * 16 + lo;
        afr[mi] = *(const bf16x8*)(&ab[buf][sc][rr * 32 + ((hi ^ ((rr >> 1) & 3)) << 3)]);
      }
#pragma unroll
      for (int mi = 0; mi < 4; ++mi)
#pragma unroll
        for (int ni = 0; ni < 4; ++ni)
          acc[mi][ni] = __builtin_amdgcn_mfma_f32_16x16x32_bf16(
              afr[mi], __builtin_bit_cast(bf16x8, bv[sc * 4 + ni]), acc[mi][ni], 0, 0, 0);
    }
    __builtin_amdgcn_s_setprio(0);
  };

  i32x4 b0[8], b1[8];
  // Prologue: top-of-body invariant = A(i)[2], B(i)[8], A(i+1)[2] in flight.
  stageA(0, 0);
  asmB(b0, 0);
  stageA(1, 1);
  int bcur3 = 0, bstg3 = 2;

  for (int s = 0; s < NM64 - 2; s += 2) {
    // even body: use b0 (i=s), load b1 (s+1)
    asmB(b1, s + 1);                                    // 20 in flight
    asm volatile("s_waitcnt vmcnt(10)" ::: "memory");   // drain A(s), B(s)
    __builtin_amdgcn_s_barrier();
    __builtin_amdgcn_sched_barrier(0);
    stageA(bstg3, s + 2);
    compute(bcur3, b0);
    bcur3 = (bcur3 == 2) ? 0 : bcur3 + 1;
    bstg3 = (bstg3 == 2) ? 0 : bstg3 + 1;
    // odd body: use b1 (s+1), load b0 (s+2)
    asmB(b0, s + 2);
    asm volatile("s_waitcnt vmcnt(10)" ::: "memory");
    __builtin_amdgcn_s_barrier();
    __builtin_amdgcn_sched_barrier(0);
    stageA(bstg3, s + 3);
    compute(bcur3, b1);
    bcur3 = (bcur3 == 2) ? 0 : bcur3 + 1;
    bstg3 = (bstg3 == 2) ? 0 : bstg3 + 1;
  }
  // body NM64-2: use b0, load last B into b1; no more stageA
  asmB(b1, NM64 - 1);
  asm volatile("s_waitcnt vmcnt(10)" ::: "memory");
  __builtin_amdgcn_s_barrier();
  __builtin_amdgcn_sched_barrier(0);
  compute(bcur3, b0);
  bcur3 = (bcur3 == 2) ? 0 : bcur3 + 1;
  // body NM64-1: use b1
  asm volatile("s_waitcnt vmcnt(0)" ::: "memory");
  __builtin_amdgcn_s_barrier();
  __builtin_amdgcn_sched_barrier(0);
  compute(bcur3, b1);

  // ---- x-skip tail: 2 K64 iterations from f32 x with W_skip ----
  if (XSK) {
#pragma unroll
    for (int sx = 0; sx < 2; ++sx) {
      __syncthreads();
      stageX(sx, sx);
      if (sx) asmBx(b1, sx); else asmBx(b0, sx);
      asm volatile("s_waitcnt vmcnt(0)" ::: "memory");
      __syncthreads();
      __builtin_amdgcn_sched_barrier(0);
      compute(sx, sx ? (const i32x4*)b1 : (const i32x4*)b0);
    }
  }

  if (!XSK) {
    bf16_t* ob = outb + ((size_t)vt * S_TOT + s0) * 256;
#pragma unroll
    for (int ni = 0; ni < 4; ++ni) {
      int o = nw * 64 + ni * 16 + lo;
      float bv = bias[o];
      float s_ = 0.f, q_ = 0.f;
#pragma unroll
      for (int mi = 0; mi < 4; ++mi)
#pragma unroll
        for (int r2 = 0; r2 < 4; ++r2) {
          int srow = mi * 16 + hi * 4 + r2;
          float v = acc[mi][ni][r2] + bv;
          ob[(size_t)srow * 256 + o] = (bf16_t)v;
          s_ += v; q_ += v * v;
        }
      s_ += __shfl_xor(s_, 16); s_ += __shfl_xor(s_, 32);
      q_ += __shfl_xor(q_, 16); q_ += __shfl_xor(q_, 32);
      if (hi == 0) {
        atomicAdd(&sum_c[vt * 256 + o], s_);
        atomicAdd(&ss_c[vt * 256 + o], q_);
      }
    }
  } else {
    float* of = outf + ((size_t)vt * S_TOT + s0) * 256;
#pragma unroll
    for (int ni = 0; ni < 4; ++ni) {
      int o = nw * 64 + ni * 16 + lo;
      float bv = bias[o] + biask[o];
#pragma unroll
      for (int mi = 0; mi < 4; ++mi)
#pragma unroll
        for (int r2 = 0; r2 < 4; ++r2) {
          int srow = mi * 16 + hi * 4 + r2;
          of[(size_t)srow * 256 + o] = acc[mi][ni][r2] + bv;
        }
    }
  }
}

extern "C" void kernel_launch(void* const* d_in, const int* in_sizes, int n_in,
                              void* d_out, int out_size, void* d_ws, size_t ws_size,
                              hipStream_t stream) {
  const float* x      = (const float*)d_in[0];
  const int*   adjc   = (const int*)d_in[1];
  const float* gn1_s  = (const float*)d_in[2];
  const float* gn1_b  = (const float*)d_in[3];
  const float* gn2_s  = (const float*)d_in[4];
  const float* gn2_b  = (const float*)d_in[5];
  const float* W_skip = (const float*)d_in[6];
  const float* b_skip = (const float*)d_in[7];
  const float* W1     = (const float*)d_in[8];
  const float* b1     = (const float*)d_in[9];
  const float* W2     = (const float*)d_in[10];
  const float* b2     = (const float*)d_in[11];
  float* out = (float*)d_out;

  float* sum1  = (float*)d_ws;           // 128
  float* ss1   = sum1 + 128;             // 128
  float* sum_c = ss1 + 128;              // 1024
  float* ss_c  = sum_c + 1024;           // 1024
  float* pad   = ss_c + 1024;            // 3072 (layout pad)
  bf16_t* W1p  = (bf16_t*)(pad + 3072);  // 294912
  bf16_t* W2p  = W1p + 294912;           // 589824
  bf16_t* Wsp  = W2p + 589824;           // 32768
  bf16_t* h1   = Wsp + 32768;            // 6291456
  bf16_t* out1 = h1 + 6291456;           // 12582912 (reused in place as h2)

  hipMemsetAsync(sum1, 0, (128 + 128 + 1024 + 1024) * sizeof(float), stream);
  prep_kernel<<<640, 256, 0, stream>>>(W1, W2, W_skip, W1p, W2p, Wsp, x, sum1, ss1);
  apply_gn1<<<3072, 256, 0, stream>>>(x, sum1, ss1, gn1_s, gn1_b, h1);
  conv_kernel<128, 18, false><<<768, 256, 0, stream>>>(
      h1, W1p, nullptr, nullptr, adjc, b1, nullptr, out1, nullptr, sum_c, ss_c);
  apply_gn2<<<6144, 256, 0, stream>>>(out1, sum_c, ss_c, gn2_s, gn2_b);
  conv_kernel<256, 36, true><<<768, 256, 0, stream>>>(
      out1, W2p, Wsp, x, adjc, b2, b_skip, nullptr, out, nullptr, nullptr);
}

// Round 13
// 131.929 us; speedup vs baseline: 1.3627x; 1.0422x over previous
//
#include <hip/hip_runtime.h>
#include <hip/hip_bf16.h>

typedef __bf16 bf16_t;
typedef __bf16 bf16x8 __attribute__((ext_vector_type(8)));
typedef float f32x4 __attribute__((ext_vector_type(4)));
typedef int i32x4 __attribute__((ext_vector_type(4)));

#define S_TOT 12288
#define F_IN 128
#define F_OUT 256
#define EPS 1e-5f

static __device__ __forceinline__ float silu_f(float v) {
  return v / (1.0f + __expf(-v));
}

static __device__ __forceinline__ void gll16(const bf16_t* g, bf16_t* l) {
  __builtin_amdgcn_global_load_lds(
      (const __attribute__((address_space(1))) void*)(const void*)g,
      (__attribute__((address_space(3))) void*)(void*)l, 16, 0, 0);
}

// ---------------- prep: pack weights (blocks 0..447) + GN1 stats (448..639) ----
// CHUNK-MAJOR pack: kcg = chunk*9 + tap. Unit (kcg, cb): lane l holds
// B[f=32*chunk+8*(l>>4)+j of W_tap][o=16cb+(l&15)] at unit*1024B + l*16B.
__global__ void prep_kernel(const float* __restrict__ W1,
                            const float* __restrict__ W2,
                            const float* __restrict__ Wsk,
                            bf16_t* __restrict__ W1p,
                            bf16_t* __restrict__ W2p,
                            bf16_t* __restrict__ Wsp,
                            const float* __restrict__ x,
                            float* __restrict__ sum1, float* __restrict__ ss1) {
  __shared__ float gs[32], gq[32];
  if (blockIdx.x < 448) {
    int w = blockIdx.x * 4 + (threadIdx.x >> 6);
    int l = threadIdx.x & 63;
    int lo = l & 15, hi = l >> 4;
    const float* src;
    bf16_t* dst;
    int fbase, obase;
    if (w < 576) {
      int kcg = w >> 4, cb = w & 15;
      int tap = kcg % 9, chunk = kcg / 9;
      src = W1 + tap * 32768;
      dst = W1p + (size_t)w * 512;
      fbase = 32 * chunk + 8 * hi; obase = 16 * cb + lo;
    } else if (w < 1728) {
      int idx = w - 576;
      int kcg = idx >> 4, cb = idx & 15;
      int tap = kcg % 9, chunk = kcg / 9;
      src = W2 + tap * 65536;
      dst = W2p + (size_t)idx * 512;
      fbase = 32 * chunk + 8 * hi; obase = 16 * cb + lo;
    } else {
      int idx = w - 1728;
      int kc = idx >> 4, cb = idx & 15;
      src = Wsk;
      dst = Wsp + (size_t)idx * 512;
      fbase = 32 * kc + 8 * hi; obase = 16 * cb + lo;
    }
    bf16x8 v;
#pragma unroll
    for (int j = 0; j < 8; ++j)
      v[j] = (bf16_t)src[(fbase + j) * 256 + obase];
    *(bf16x8*)(dst + l * 8) = v;
  } else {
    int blk = blockIdx.x - 448;
    int vt = blk & 3;
    int s0 = (blk >> 2) * 256;
    int t = threadIdx.x;
    int col = t & 31, ro = t >> 5;
    float s_ = 0.f, q_ = 0.f;
    const f32x4* xp = (const f32x4*)(x + ((size_t)vt * S_TOT + s0) * F_IN);
#pragma unroll 4
    for (int it = 0; it < 32; ++it) {
      f32x4 v = xp[(size_t)(it * 8 + ro) * 32 + col];
      s_ += v[0] + v[1] + v[2] + v[3];
      q_ += v[0]*v[0] + v[1]*v[1] + v[2]*v[2] + v[3]*v[3];
    }
    if (t < 32) { gs[t] = 0.f; gq[t] = 0.f; }
    __syncthreads();
    atomicAdd(&gs[col], s_);
    atomicAdd(&gq[col], q_);
    __syncthreads();
    if (t < 32) {
      atomicAdd(&sum1[vt * 32 + t], gs[t]);
      atomicAdd(&ss1[vt * 32 + t], gq[t]);
    }
  }
}

// ---------------- apply GN1 (affine inline) + SiLU -> h1 ----------------
__global__ void apply_gn1(const float* __restrict__ x,
                          const float* __restrict__ sum1, const float* __restrict__ ss1,
                          const float* __restrict__ gs, const float* __restrict__ gb,
                          bf16_t* __restrict__ h1) {
  size_t base = ((size_t)blockIdx.x * 256 + threadIdx.x) * 8;
  int vt = (int)(base / ((size_t)S_TOT * F_IN));
  int c0 = (int)(base & (F_IN - 1));
  const f32x4* xp = (const f32x4*)(x + base);
  f32x4 v0 = xp[0], v1 = xp[1];
  float N = (float)(S_TOT * 4);
  bf16x8 o;
#pragma unroll
  for (int gi = 0; gi < 2; ++gi) {
    int g = (c0 >> 2) + gi;
    float mean = sum1[vt * 32 + g] / N;
    float var = ss1[vt * 32 + g] / N - mean * mean;
    float r = rsqrtf(var + EPS);
    f32x4 v = gi ? v1 : v0;
#pragma unroll
    for (int j = 0; j < 4; ++j) {
      int c = g * 4 + j;
      float a = r * gs[c];
      float b = gb[c] - mean * a;
      o[gi * 4 + j] = (bf16_t)silu_f(v[j] * a + b);
    }
  }
  *(bf16x8*)(h1 + base) = o;
}

// ---------------- apply GN2 (affine inline) + SiLU in place ----------------
__global__ void apply_gn2(bf16_t* __restrict__ h,
                          const float* __restrict__ sum_c, const float* __restrict__ ss_c,
                          const float* __restrict__ gs, const float* __restrict__ gb) {
  size_t base = ((size_t)blockIdx.x * 256 + threadIdx.x) * 8;
  int vt = (int)(base / ((size_t)S_TOT * F_OUT));
  int c0 = (int)(base & (F_OUT - 1));
  int g = c0 >> 3;
  bf16x8 v = *(const bf16x8*)(h + base);
  float sg = 0.f, qg = 0.f;
#pragma unroll
  for (int j = 0; j < 8; ++j) {
    sg += sum_c[vt * 256 + g * 8 + j];
    qg += ss_c[vt * 256 + g * 8 + j];
  }
  float N = (float)(S_TOT * 8);
  float mean = sg / N;
  float var = qg / N - mean * mean;
  float r = rsqrtf(var + EPS);
  bf16x8 o;
#pragma unroll
  for (int j = 0; j < 8; ++j) {
    int c = g * 8 + j;
    float a = r * gs[c];
    float b = gb[c] - mean * a;
    o[j] = (bf16_t)silu_f((float)v[j] * a + b);
  }
  *(bf16x8*)(h + base) = o;
}

// ---------------- unified gather-conv GEMM v13 ----------------
// Block 96 rows x 256 cols, 4 waves of 96x64, acc[6][4] (96 acc regs).
// Grid 512 = EXACTLY 2 blocks/CU (two INDEPENDENT blocks drift-overlap, unlike
// R11's barrier-locked same-block waves). K64 per barrier (R12's win kept).
// Per CU-round: MFMA/SIMD = 2x48x19.4 = 1860cy (max pipe), L1 = 88KB = 1375cy,
// LDS ~1450cy -> MFMA-led. A: 3 gll16/wave (12 groups of 16 rows over 2 chunks).
// B: 8 asm dwordx4 (chunk pair kcg, kcg+9). Uniform 11 VMEM/wave/iter ->
// steady vmcnt(11): A 2 iters in flight (~HBM-cover), B 1 iter (L2-hot).
template<int RE, int NM64, bool XSK>
__global__ __launch_bounds__(256, 2) void conv_kernel(
    const bf16_t* __restrict__ hsrc, const bf16_t* __restrict__ Wp,
    const bf16_t* __restrict__ Wsp, const float* __restrict__ x,
    const int* __restrict__ adjc, const float* __restrict__ bias,
    const float* __restrict__ biask, bf16_t* __restrict__ outb,
    float* __restrict__ outf, float* __restrict__ sum_c, float* __restrict__ ss_c) {
  const int tid = threadIdx.x;
  const int wv = tid >> 6, l = tid & 63;
  const int lo = l & 15, hi = l >> 4;
  const int nw = wv;

  int swz = ((blockIdx.x & 7) << 6) + (blockIdx.x >> 3);   // bijective: 512 = 8*64
  int vt = swz >> 7;
  int rem = swz & 127;
  int s0 = rem * 96;

  __shared__ int adjs[864];
  __shared__ bf16_t ab[3][2][3072];   // ring-3, 2 chunks, 96 rows x 32 (64B rows)

  for (int i = tid; i < 864; i += 256) adjs[i] = adjc[s0 * 9 + i];
  __syncthreads();

  const bf16_t* hb = hsrc + (size_t)vt * ((size_t)S_TOT * RE);

  // A-stage for K64 iteration i (tap=i%9, cpair=i/9): 3 gll16 per wave.
  // Flat unit u = wv*3 + j2 (0..11): chunk = u/6, 16-row group g = u%6.
  auto stageA = [&](int buf, int i) {
    int tap = i % 9, cpair = i / 9;
#pragma unroll
    for (int j2 = 0; j2 < 3; ++j2) {
      int u = wv * 3 + j2;
      int chunk = u / 6, grp = u % 6;
      int row = grp * 16 + (l >> 2);
      int segs = (l & 3) ^ ((row >> 1) & 3);
      const bf16_t* g = hb + (size_t)adjs[row * 9 + tap] * RE + cpair * 64 + chunk * 32 + segs * 8;
      gll16(g, &ab[buf][chunk][grp * 512]);
    }
  };

  // B-stage: 8 asm dwordx4 into regs; chunk pair = units kcg, kcg+9.
  auto asmB = [&](i32x4* dst, int i) {
    int tap = i % 9, cpair = i / 9;
    const bf16_t* pa = Wp + (size_t)(18 * cpair + tap) * 8192 + nw * 2048 + l * 8;
    const bf16_t* pb = pa + 9 * 8192;
    asm volatile(
        "global_load_dwordx4 %0, %4, off\n\t"
        "global_load_dwordx4 %1, %4, off offset:1024\n\t"
        "global_load_dwordx4 %2, %4, off offset:2048\n\t"
        "global_load_dwordx4 %3, %4, off offset:3072"
        : "=&v"(dst[0]), "=&v"(dst[1]), "=&v"(dst[2]), "=&v"(dst[3])
        : "v"(pa));
    asm volatile(
        "global_load_dwordx4 %0, %4, off\n\t"
        "global_load_dwordx4 %1, %4, off offset:1024\n\t"
        "global_load_dwordx4 %2, %4, off offset:2048\n\t"
        "global_load_dwordx4 %3, %4, off offset:3072"
        : "=&v"(dst[4]), "=&v"(dst[5]), "=&v"(dst[6]), "=&v"(dst[7])
        : "v"(pb));
  };

  // x-skip B: chunk pair 2sx, 2sx+1 of Wsp (adjacent units).
  auto asmBx = [&](i32x4* dst, int sx) {
    const bf16_t* pa = Wsp + (size_t)(2 * sx) * 8192 + nw * 2048 + l * 8;
    const bf16_t* pb = pa + 8192;
    asm volatile(
        "global_load_dwordx4 %0, %4, off\n\t"
        "global_load_dwordx4 %1, %4, off offset:1024\n\t"
        "global_load_dwordx4 %2, %4, off offset:2048\n\t"
        "global_load_dwordx4 %3, %4, off offset:3072"
        : "=&v"(dst[0]), "=&v"(dst[1]), "=&v"(dst[2]), "=&v"(dst[3])
        : "v"(pa));
    asm volatile(
        "global_load_dwordx4 %0, %4, off\n\t"
        "global_load_dwordx4 %1, %4, off offset:1024\n\t"
        "global_load_dwordx4 %2, %4, off offset:2048\n\t"
        "global_load_dwordx4 %3, %4, off offset:3072"
        : "=&v"(dst[4]), "=&v"(dst[5]), "=&v"(dst[6]), "=&v"(dst[7])
        : "v"(pb));
  };

  // x-skip stage: f32 -> bf16 reg path, 96 rows x 2 chunks of slice sx.
  // 768 bf16x8 writes, 3 per thread: idx = j*256+tid -> row=idx/8, sc, q.
  auto stageX = [&](int buf, int sx) {
#pragma unroll
    for (int j = 0; j < 3; ++j) {
      int idx = j * 256 + tid;
      int row = idx >> 3, rest = idx & 7;
      int sc = rest >> 2, q = rest & 3;
      const float* xr = x + ((size_t)vt * S_TOT + s0 + row) * F_IN + sx * 64 + sc * 32 + q * 8;
      f32x4 xv0 = *(const f32x4*)(xr);
      f32x4 xv1 = *(const f32x4*)(xr + 4);
      bf16x8 w;
#pragma unroll
      for (int jj = 0; jj < 4; ++jj) {
        w[jj] = (bf16_t)xv0[jj];
        w[4 + jj] = (bf16_t)xv1[jj];
      }
      *(bf16x8*)(&ab[buf][sc][row * 32 + ((q ^ ((row >> 1) & 3)) << 3)]) = w;
    }
  };

  f32x4 acc[6][4] = {};
  auto compute = [&](int buf, const i32x4* bv) {
    __builtin_amdgcn_s_setprio(1);
#pragma unroll
    for (int sc = 0; sc < 2; ++sc) {
#pragma unroll
      for (int mi = 0; mi < 6; ++mi) {
        int rr = mi * 16 + lo;
        bf16x8 afr = *(const bf16x8*)(&ab[buf][sc][rr * 32 + ((hi ^ ((rr >> 1) & 3)) << 3)]);
#pragma unroll
        for (int ni = 0; ni < 4; ++ni)
          acc[mi][ni] = __builtin_amdgcn_mfma_f32_16x16x32_bf16(
              afr, __builtin_bit_cast(bf16x8, bv[sc * 4 + ni]), acc[mi][ni], 0, 0, 0);
      }
    }
    __builtin_amdgcn_s_setprio(0);
  };

  i32x4 b0[8], b1[8];
  // Prologue: top-of-body invariant = A(i)[3], B(i)[8], A(i+1)[3] in flight.
  stageA(0, 0);
  asmB(b0, 0);
  stageA(1, 1);
  int bcur3 = 0, bstg3 = 2;

  for (int s = 0; s < NM64 - 2; s += 2) {
    // even body: use b0 (i=s), load b1 (s+1)
    asmB(b1, s + 1);                                    // 22 in flight
    asm volatile("s_waitcnt vmcnt(11)" ::: "memory");   // drain A(s), B(s)
    __builtin_amdgcn_s_barrier();
    __builtin_amdgcn_sched_barrier(0);
    stageA(bstg3, s + 2);
    compute(bcur3, b0);
    bcur3 = (bcur3 == 2) ? 0 : bcur3 + 1;
    bstg3 = (bstg3 == 2) ? 0 : bstg3 + 1;
    // odd body: use b1 (s+1), load b0 (s+2)
    asmB(b0, s + 2);
    asm volatile("s_waitcnt vmcnt(11)" ::: "memory");
    __builtin_amdgcn_s_barrier();
    __builtin_amdgcn_sched_barrier(0);
    stageA(bstg3, s + 3);
    compute(bcur3, b1);
    bcur3 = (bcur3 == 2) ? 0 : bcur3 + 1;
    bstg3 = (bstg3 == 2) ? 0 : bstg3 + 1;
  }
  // body NM64-2: use b0, load last B into b1; no more stageA
  asmB(b1, NM64 - 1);
  asm volatile("s_waitcnt vmcnt(11)" ::: "memory");
  __builtin_amdgcn_s_barrier();
  __builtin_amdgcn_sched_barrier(0);
  compute(bcur3, b0);
  bcur3 = (bcur3 == 2) ? 0 : bcur3 + 1;
  // body NM64-1: use b1
  asm volatile("s_waitcnt vmcnt(0)" ::: "memory");
  __builtin_amdgcn_s_barrier();
  __builtin_amdgcn_sched_barrier(0);
  compute(bcur3, b1);

  // ---- x-skip tail: 2 K64 iterations from f32 x with W_skip ----
  if (XSK) {
#pragma unroll
    for (int sx = 0; sx < 2; ++sx) {
      __syncthreads();
      stageX(sx, sx);
      if (sx) asmBx(b1, sx); else asmBx(b0, sx);
      asm volatile("s_waitcnt vmcnt(0)" ::: "memory");
      __syncthreads();
      __builtin_amdgcn_sched_barrier(0);
      compute(sx, sx ? (const i32x4*)b1 : (const i32x4*)b0);
    }
  }

  if (!XSK) {
    bf16_t* ob = outb + ((size_t)vt * S_TOT + s0) * 256;
#pragma unroll
    for (int ni = 0; ni < 4; ++ni) {
      int o = nw * 64 + ni * 16 + lo;
      float bv = bias[o];
      float s_ = 0.f, q_ = 0.f;
#pragma unroll
      for (int mi = 0; mi < 6; ++mi)
#pragma unroll
        for (int r2 = 0; r2 < 4; ++r2) {
          int srow = mi * 16 + hi * 4 + r2;
          float v = acc[mi][ni][r2] + bv;
          ob[(size_t)srow * 256 + o] = (bf16_t)v;
          s_ += v; q_ += v * v;
        }
      s_ += __shfl_xor(s_, 16); s_ += __shfl_xor(s_, 32);
      q_ += __shfl_xor(q_, 16); q_ += __shfl_xor(q_, 32);
      if (hi == 0) {
        atomicAdd(&sum_c[vt * 256 + o], s_);
        atomicAdd(&ss_c[vt * 256 + o], q_);
      }
    }
  } else {
    float* of = outf + ((size_t)vt * S_TOT + s0) * 256;
#pragma unroll
    for (int ni = 0; ni < 4; ++ni) {
      int o = nw * 64 + ni * 16 + lo;
      float bv = bias[o] + biask[o];
#pragma unroll
      for (int mi = 0; mi < 6; ++mi)
#pragma unroll
        for (int r2 = 0; r2 < 4; ++r2) {
          int srow = mi * 16 + hi * 4 + r2;
          of[(size_t)srow * 256 + o] = acc[mi][ni][r2] + bv;
        }
    }
  }
}

extern "C" void kernel_launch(void* const* d_in, const int* in_sizes, int n_in,
                              void* d_out, int out_size, void* d_ws, size_t ws_size,
                              hipStream_t stream) {
  const float* x      = (const float*)d_in[0];
  const int*   adjc   = (const int*)d_in[1];
  const float* gn1_s  = (const float*)d_in[2];
  const float* gn1_b  = (const float*)d_in[3];
  const float* gn2_s  = (const float*)d_in[4];
  const float* gn2_b  = (const float*)d_in[5];
  const float* W_skip = (const float*)d_in[6];
  const float* b_skip = (const float*)d_in[7];
  const float* W1     = (const float*)d_in[8];
  const float* b1     = (const float*)d_in[9];
  const float* W2     = (const float*)d_in[10];
  const float* b2     = (const float*)d_in[11];
  float* out = (float*)d_out;

  float* sum1  = (float*)d_ws;           // 128
  float* ss1   = sum1 + 128;             // 128
  float* sum_c = ss1 + 128;              // 1024
  float* ss_c  = sum_c + 1024;           // 1024
  float* pad   = ss_c + 1024;            // 3072 (layout pad)
  bf16_t* W1p  = (bf16_t*)(pad + 3072);  // 294912
  bf16_t* W2p  = W1p + 294912;           // 589824
  bf16_t* Wsp  = W2p + 589824;           // 32768
  bf16_t* h1   = Wsp + 32768;            // 6291456
  bf16_t* out1 = h1 + 6291456;           // 12582912 (reused in place as h2)

  hipMemsetAsync(sum1, 0, (128 + 128 + 1024 + 1024) * sizeof(float), stream);
  prep_kernel<<<640, 256, 0, stream>>>(W1, W2, W_skip, W1p, W2p, Wsp, x, sum1, ss1);
  apply_gn1<<<3072, 256, 0, stream>>>(x, sum1, ss1, gn1_s, gn1_b, h1);
  conv_kernel<128, 18, false><<<512, 256, 0, stream>>>(
      h1, W1p, nullptr, nullptr, adjc, b1, nullptr, out1, nullptr, sum_c, ss_c);
  apply_gn2<<<6144, 256, 0, stream>>>(out1, sum_c, ss_c, gn2_s, gn2_b);
  conv_kernel<256, 36, true><<<512, 256, 0, stream>>>(
      out1, W2p, Wsp, x, adjc, b2, b_skip, nullptr, out, nullptr, nullptr);
}

// Round 14
// 128.203 us; speedup vs baseline: 1.4023x; 1.0291x over previous
//
#include <hip/hip_runtime.h>
#include <hip/hip_bf16.h>

typedef __bf16 bf16_t;
typedef __bf16 bf16x8 __attribute__((ext_vector_type(8)));
typedef float f32x4 __attribute__((ext_vector_type(4)));
typedef int i32x4 __attribute__((ext_vector_type(4)));

#define S_TOT 12288
#define F_IN 128
#define F_OUT 256
#define EPS 1e-5f

static __device__ __forceinline__ float silu_f(float v) {
  return v / (1.0f + __expf(-v));
}

static __device__ __forceinline__ void gll16(const bf16_t* g, bf16_t* l) {
  __builtin_amdgcn_global_load_lds(
      (const __attribute__((address_space(1))) void*)(const void*)g,
      (__attribute__((address_space(3))) void*)(void*)l, 16, 0, 0);
}

// ---------------- prep: pack weights (blocks 0..447) + GN1 stats (448..639) ----
// CHUNK-MAJOR pack: kcg = chunk*9 + tap. Unit (kcg, cb): lane l holds
// B[f=32*chunk+8*(l>>4)+j of W_tap][o=16cb+(l&15)] at unit*1024B + l*16B.
__global__ void prep_kernel(const float* __restrict__ W1,
                            const float* __restrict__ W2,
                            const float* __restrict__ Wsk,
                            bf16_t* __restrict__ W1p,
                            bf16_t* __restrict__ W2p,
                            bf16_t* __restrict__ Wsp,
                            const float* __restrict__ x,
                            float* __restrict__ sum1, float* __restrict__ ss1) {
  __shared__ float gs[32], gq[32];
  if (blockIdx.x < 448) {
    int w = blockIdx.x * 4 + (threadIdx.x >> 6);
    int l = threadIdx.x & 63;
    int lo = l & 15, hi = l >> 4;
    const float* src;
    bf16_t* dst;
    int fbase, obase;
    if (w < 576) {
      int kcg = w >> 4, cb = w & 15;
      int tap = kcg % 9, chunk = kcg / 9;
      src = W1 + tap * 32768;
      dst = W1p + (size_t)w * 512;
      fbase = 32 * chunk + 8 * hi; obase = 16 * cb + lo;
    } else if (w < 1728) {
      int idx = w - 576;
      int kcg = idx >> 4, cb = idx & 15;
      int tap = kcg % 9, chunk = kcg / 9;
      src = W2 + tap * 65536;
      dst = W2p + (size_t)idx * 512;
      fbase = 32 * chunk + 8 * hi; obase = 16 * cb + lo;
    } else {
      int idx = w - 1728;
      int kc = idx >> 4, cb = idx & 15;
      src = Wsk;
      dst = Wsp + (size_t)idx * 512;
      fbase = 32 * kc + 8 * hi; obase = 16 * cb + lo;
    }
    bf16x8 v;
#pragma unroll
    for (int j = 0; j < 8; ++j)
      v[j] = (bf16_t)src[(fbase + j) * 256 + obase];
    *(bf16x8*)(dst + l * 8) = v;
  } else {
    int blk = blockIdx.x - 448;
    int vt = blk & 3;
    int s0 = (blk >> 2) * 256;
    int t = threadIdx.x;
    int col = t & 31, ro = t >> 5;
    float s_ = 0.f, q_ = 0.f;
    const f32x4* xp = (const f32x4*)(x + ((size_t)vt * S_TOT + s0) * F_IN);
#pragma unroll 4
    for (int it = 0; it < 32; ++it) {
      f32x4 v = xp[(size_t)(it * 8 + ro) * 32 + col];
      s_ += v[0] + v[1] + v[2] + v[3];
      q_ += v[0]*v[0] + v[1]*v[1] + v[2]*v[2] + v[3]*v[3];
    }
    if (t < 32) { gs[t] = 0.f; gq[t] = 0.f; }
    __syncthreads();
    atomicAdd(&gs[col], s_);
    atomicAdd(&gq[col], q_);
    __syncthreads();
    if (t < 32) {
      atomicAdd(&sum1[vt * 32 + t], gs[t]);
      atomicAdd(&ss1[vt * 32 + t], gq[t]);
    }
  }
}

// ---------------- apply GN1 + SiLU -> h1 (block-level coeffs in LDS) ----------
// 768 blocks x 256 thr x 32 elems. Block = 8192 f32 = 64 rows x 128 ch, one vt.
// Threads 0..31 build the 128 affine coeffs once; main loop is pure streaming
// (channel phase invariant under the 2048-elem stride -> coeffs stay in regs).
__global__ void apply_gn1(const float* __restrict__ x,
                          const float* __restrict__ sum1, const float* __restrict__ ss1,
                          const float* __restrict__ gs, const float* __restrict__ gb,
                          bf16_t* __restrict__ h1) {
  __shared__ float aco[128], bco[128];
  int blk = blockIdx.x;
  int vt = blk / 192;
  size_t base = (size_t)blk * 8192;
  int t = threadIdx.x;
  if (t < 32) {
    float N = (float)(S_TOT * 4);
    float mean = sum1[vt * 32 + t] / N;
    float var = ss1[vt * 32 + t] / N - mean * mean;
    float r = rsqrtf(var + EPS);
#pragma unroll
    for (int j = 0; j < 4; ++j) {
      int c = t * 4 + j;
      float a = r * gs[c];
      aco[c] = a;
      bco[c] = gb[c] - mean * a;
    }
  }
  __syncthreads();
  int c0 = (t * 8) & 127;
  f32x4 A0 = *(const f32x4*)&aco[c0];
  f32x4 A1 = *(const f32x4*)&aco[c0 + 4];
  f32x4 B0 = *(const f32x4*)&bco[c0];
  f32x4 B1 = *(const f32x4*)&bco[c0 + 4];
#pragma unroll
  for (int i = 0; i < 4; ++i) {
    size_t idx = base + (size_t)i * 2048 + t * 8;
    const f32x4* xp = (const f32x4*)(x + idx);
    f32x4 v0 = xp[0], v1 = xp[1];
    bf16x8 o;
#pragma unroll
    for (int j = 0; j < 4; ++j) o[j] = (bf16_t)silu_f(v0[j] * A0[j] + B0[j]);
#pragma unroll
    for (int j = 0; j < 4; ++j) o[4 + j] = (bf16_t)silu_f(v1[j] * A1[j] + B1[j]);
    *(bf16x8*)(h1 + idx) = o;
  }
}

// ---------------- apply GN2 + SiLU in place (block-level coeffs in LDS) ------
// 1536 blocks x 256 thr x 32 elems. Block = 8192 bf16 = 32 rows x 256 ch.
__global__ void apply_gn2(bf16_t* __restrict__ h,
                          const float* __restrict__ sum_c, const float* __restrict__ ss_c,
                          const float* __restrict__ gs, const float* __restrict__ gb) {
  __shared__ float aco[256], bco[256];
  int blk = blockIdx.x;
  int vt = blk / 384;
  size_t base = (size_t)blk * 8192;
  int t = threadIdx.x;
  {
    int c = t;                         // thread t computes channel t's coeffs
    int g = c >> 3;
    float sg = 0.f, qg = 0.f;
#pragma unroll
    for (int j = 0; j < 8; ++j) {
      sg += sum_c[vt * 256 + g * 8 + j];
      qg += ss_c[vt * 256 + g * 8 + j];
    }
    float N = (float)(S_TOT * 8);
    float mean = sg / N;
    float var = qg / N - mean * mean;
    float r = rsqrtf(var + EPS);
    float a = r * gs[c];
    aco[c] = a;
    bco[c] = gb[c] - mean * a;
  }
  __syncthreads();
  int c0 = (t * 8) & 255;
  f32x4 A0 = *(const f32x4*)&aco[c0];
  f32x4 A1 = *(const f32x4*)&aco[c0 + 4];
  f32x4 B0 = *(const f32x4*)&bco[c0];
  f32x4 B1 = *(const f32x4*)&bco[c0 + 4];
#pragma unroll
  for (int i = 0; i < 4; ++i) {
    size_t idx = base + (size_t)i * 2048 + t * 8;
    bf16x8 v = *(const bf16x8*)(h + idx);
    bf16x8 o;
#pragma unroll
    for (int j = 0; j < 4; ++j) o[j] = (bf16_t)silu_f((float)v[j] * A0[j] + B0[j]);
#pragma unroll
    for (int j = 0; j < 4; ++j) o[4 + j] = (bf16_t)silu_f((float)v[4 + j] * A1[j] + B1[j]);
    *(bf16x8*)(h + idx) = o;
  }
}

// ---------------- unified gather-conv GEMM v13 (unchanged) ----------------
// Block 96 rows x 256 cols, 4 waves of 96x64, acc[6][4]. Grid 512 = 2 blocks/CU.
// K64 per barrier; ring-3 A via gll; B 8 asm dwordx4 reg-dbuf; steady vmcnt(11).
template<int RE, int NM64, bool XSK>
__global__ __launch_bounds__(256, 2) void conv_kernel(
    const bf16_t* __restrict__ hsrc, const bf16_t* __restrict__ Wp,
    const bf16_t* __restrict__ Wsp, const float* __restrict__ x,
    const int* __restrict__ adjc, const float* __restrict__ bias,
    const float* __restrict__ biask, bf16_t* __restrict__ outb,
    float* __restrict__ outf, float* __restrict__ sum_c, float* __restrict__ ss_c) {
  const int tid = threadIdx.x;
  const int wv = tid >> 6, l = tid & 63;
  const int lo = l & 15, hi = l >> 4;
  const int nw = wv;

  int swz = ((blockIdx.x & 7) << 6) + (blockIdx.x >> 3);   // bijective: 512 = 8*64
  int vt = swz >> 7;
  int rem = swz & 127;
  int s0 = rem * 96;

  __shared__ int adjs[864];
  __shared__ bf16_t ab[3][2][3072];   // ring-3, 2 chunks, 96 rows x 32 (64B rows)

  for (int i = tid; i < 864; i += 256) adjs[i] = adjc[s0 * 9 + i];
  __syncthreads();

  const bf16_t* hb = hsrc + (size_t)vt * ((size_t)S_TOT * RE);

  auto stageA = [&](int buf, int i) {
    int tap = i % 9, cpair = i / 9;
#pragma unroll
    for (int j2 = 0; j2 < 3; ++j2) {
      int u = wv * 3 + j2;
      int chunk = u / 6, grp = u % 6;
      int row = grp * 16 + (l >> 2);
      int segs = (l & 3) ^ ((row >> 1) & 3);
      const bf16_t* g = hb + (size_t)adjs[row * 9 + tap] * RE + cpair * 64 + chunk * 32 + segs * 8;
      gll16(g, &ab[buf][chunk][grp * 512]);
    }
  };

  auto asmB = [&](i32x4* dst, int i) {
    int tap = i % 9, cpair = i / 9;
    const bf16_t* pa = Wp + (size_t)(18 * cpair + tap) * 8192 + nw * 2048 + l * 8;
    const bf16_t* pb = pa + 9 * 8192;
    asm volatile(
        "global_load_dwordx4 %0, %4, off\n\t"
        "global_load_dwordx4 %1, %4, off offset:1024\n\t"
        "global_load_dwordx4 %2, %4, off offset:2048\n\t"
        "global_load_dwordx4 %3, %4, off offset:3072"
        : "=&v"(dst[0]), "=&v"(dst[1]), "=&v"(dst[2]), "=&v"(dst[3])
        : "v"(pa));
    asm volatile(
        "global_load_dwordx4 %0, %4, off\n\t"
        "global_load_dwordx4 %1, %4, off offset:1024\n\t"
        "global_load_dwordx4 %2, %4, off offset:2048\n\t"
        "global_load_dwordx4 %3, %4, off offset:3072"
        : "=&v"(dst[4]), "=&v"(dst[5]), "=&v"(dst[6]), "=&v"(dst[7])
        : "v"(pb));
  };

  auto asmBx = [&](i32x4* dst, int sx) {
    const bf16_t* pa = Wsp + (size_t)(2 * sx) * 8192 + nw * 2048 + l * 8;
    const bf16_t* pb = pa + 8192;
    asm volatile(
        "global_load_dwordx4 %0, %4, off\n\t"
        "global_load_dwordx4 %1, %4, off offset:1024\n\t"
        "global_load_dwordx4 %2, %4, off offset:2048\n\t"
        "global_load_dwordx4 %3, %4, off offset:3072"
        : "=&v"(dst[0]), "=&v"(dst[1]), "=&v"(dst[2]), "=&v"(dst[3])
        : "v"(pa));
    asm volatile(
        "global_load_dwordx4 %0, %4, off\n\t"
        "global_load_dwordx4 %1, %4, off offset:1024\n\t"
        "global_load_dwordx4 %2, %4, off offset:2048\n\t"
        "global_load_dwordx4 %3, %4, off offset:3072"
        : "=&v"(dst[4]), "=&v"(dst[5]), "=&v"(dst[6]), "=&v"(dst[7])
        : "v"(pb));
  };

  auto stageX = [&](int buf, int sx) {
#pragma unroll
    for (int j = 0; j < 3; ++j) {
      int idx = j * 256 + tid;
      int row = idx >> 3, rest = idx & 7;
      int sc = rest >> 2, q = rest & 3;
      const float* xr = x + ((size_t)vt * S_TOT + s0 + row) * F_IN + sx * 64 + sc * 32 + q * 8;
      f32x4 xv0 = *(const f32x4*)(xr);
      f32x4 xv1 = *(const f32x4*)(xr + 4);
      bf16x8 w;
#pragma unroll
      for (int jj = 0; jj < 4; ++jj) {
        w[jj] = (bf16_t)xv0[jj];
        w[4 + jj] = (bf16_t)xv1[jj];
      }
      *(bf16x8*)(&ab[buf][sc][row * 32 + ((q ^ ((row >> 1) & 3)) << 3)]) = w;
    }
  };

  f32x4 acc[6][4] = {};
  auto compute = [&](int buf, const i32x4* bv) {
    __builtin_amdgcn_s_setprio(1);
#pragma unroll
    for (int sc = 0; sc < 2; ++sc) {
#pragma unroll
      for (int mi = 0; mi < 6; ++mi) {
        int rr = mi * 16 + lo;
        bf16x8 afr = *(const bf16x8*)(&ab[buf][sc][rr * 32 + ((hi ^ ((rr >> 1) & 3)) << 3)]);
#pragma unroll
        for (int ni = 0; ni < 4; ++ni)
          acc[mi][ni] = __builtin_amdgcn_mfma_f32_16x16x32_bf16(
              afr, __builtin_bit_cast(bf16x8, bv[sc * 4 + ni]), acc[mi][ni], 0, 0, 0);
      }
    }
    __builtin_amdgcn_s_setprio(0);
  };

  i32x4 b0[8], b1[8];
  stageA(0, 0);
  asmB(b0, 0);
  stageA(1, 1);
  int bcur3 = 0, bstg3 = 2;

  for (int s = 0; s < NM64 - 2; s += 2) {
    asmB(b1, s + 1);
    asm volatile("s_waitcnt vmcnt(11)" ::: "memory");
    __builtin_amdgcn_s_barrier();
    __builtin_amdgcn_sched_barrier(0);
    stageA(bstg3, s + 2);
    compute(bcur3, b0);
    bcur3 = (bcur3 == 2) ? 0 : bcur3 + 1;
    bstg3 = (bstg3 == 2) ? 0 : bstg3 + 1;
    asmB(b0, s + 2);
    asm volatile("s_waitcnt vmcnt(11)" ::: "memory");
    __builtin_amdgcn_s_barrier();
    __builtin_amdgcn_sched_barrier(0);
    stageA(bstg3, s + 3);
    compute(bcur3, b1);
    bcur3 = (bcur3 == 2) ? 0 : bcur3 + 1;
    bstg3 = (bstg3 == 2) ? 0 : bstg3 + 1;
  }
  asmB(b1, NM64 - 1);
  asm volatile("s_waitcnt vmcnt(11)" ::: "memory");
  __builtin_amdgcn_s_barrier();
  __builtin_amdgcn_sched_barrier(0);
  compute(bcur3, b0);
  bcur3 = (bcur3 == 2) ? 0 : bcur3 + 1;
  asm volatile("s_waitcnt vmcnt(0)" ::: "memory");
  __builtin_amdgcn_s_barrier();
  __builtin_amdgcn_sched_barrier(0);
  compute(bcur3, b1);

  if (XSK) {
#pragma unroll
    for (int sx = 0; sx < 2; ++sx) {
      __syncthreads();
      stageX(sx, sx);
      if (sx) asmBx(b1, sx); else asmBx(b0, sx);
      asm volatile("s_waitcnt vmcnt(0)" ::: "memory");
      __syncthreads();
      __builtin_amdgcn_sched_barrier(0);
      compute(sx, sx ? (const i32x4*)b1 : (const i32x4*)b0);
    }
  }

  if (!XSK) {
    bf16_t* ob = outb + ((size_t)vt * S_TOT + s0) * 256;
#pragma unroll
    for (int ni = 0; ni < 4; ++ni) {
      int o = nw * 64 + ni * 16 + lo;
      float bv = bias[o];
      float s_ = 0.f, q_ = 0.f;
#pragma unroll
      for (int mi = 0; mi < 6; ++mi)
#pragma unroll
        for (int r2 = 0; r2 < 4; ++r2) {
          int srow = mi * 16 + hi * 4 + r2;
          float v = acc[mi][ni][r2] + bv;
          ob[(size_t)srow * 256 + o] = (bf16_t)v;
          s_ += v; q_ += v * v;
        }
      s_ += __shfl_xor(s_, 16); s_ += __shfl_xor(s_, 32);
      q_ += __shfl_xor(q_, 16); q_ += __shfl_xor(q_, 32);
      if (hi == 0) {
        atomicAdd(&sum_c[vt * 256 + o], s_);
        atomicAdd(&ss_c[vt * 256 + o], q_);
      }
    }
  } else {
    float* of = outf + ((size_t)vt * S_TOT + s0) * 256;
#pragma unroll
    for (int ni = 0; ni < 4; ++ni) {
      int o = nw * 64 + ni * 16 + lo;
      float bv = bias[o] + biask[o];
#pragma unroll
      for (int mi = 0; mi < 6; ++mi)
#pragma unroll
        for (int r2 = 0; r2 < 4; ++r2) {
          int srow = mi * 16 + hi * 4 + r2;
          of[(size_t)srow * 256 + o] = acc[mi][ni][r2] + bv;
        }
    }
  }
}

extern "C" void kernel_launch(void* const* d_in, const int* in_sizes, int n_in,
                              void* d_out, int out_size, void* d_ws, size_t ws_size,
                              hipStream_t stream) {
  const float* x      = (const float*)d_in[0];
  const int*   adjc   = (const int*)d_in[1];
  const float* gn1_s  = (const float*)d_in[2];
  const float* gn1_b  = (const float*)d_in[3];
  const float* gn2_s  = (const float*)d_in[4];
  const float* gn2_b  = (const float*)d_in[5];
  const float* W_skip = (const float*)d_in[6];
  const float* b_skip = (const float*)d_in[7];
  const float* W1     = (const float*)d_in[8];
  const float* b1     = (const float*)d_in[9];
  const float* W2     = (const float*)d_in[10];
  const float* b2     = (const float*)d_in[11];
  float* out = (float*)d_out;

  float* sum1  = (float*)d_ws;           // 128
  float* ss1   = sum1 + 128;             // 128
  float* sum_c = ss1 + 128;              // 1024
  float* ss_c  = sum_c + 1024;           // 1024
  float* pad   = ss_c + 1024;            // 3072 (layout pad)
  bf16_t* W1p  = (bf16_t*)(pad + 3072);  // 294912
  bf16_t* W2p  = W1p + 294912;           // 589824
  bf16_t* Wsp  = W2p + 589824;           // 32768
  bf16_t* h1   = Wsp + 32768;            // 6291456
  bf16_t* out1 = h1 + 6291456;           // 12582912 (reused in place as h2)

  hipMemsetAsync(sum1, 0, (128 + 128 + 1024 + 1024) * sizeof(float), stream);
  prep_kernel<<<640, 256, 0, stream>>>(W1, W2, W_skip, W1p, W2p, Wsp, x, sum1, ss1);
  apply_gn1<<<768, 256, 0, stream>>>(x, sum1, ss1, gn1_s, gn1_b, h1);
  conv_kernel<128, 18, false><<<512, 256, 0, stream>>>(
      h1, W1p, nullptr, nullptr, adjc, b1, nullptr, out1, nullptr, sum_c, ss_c);
  apply_gn2<<<1536, 256, 0, stream>>>(out1, sum_c, ss_c, gn2_s, gn2_b);
  conv_kernel<256, 36, true><<<512, 256, 0, stream>>>(
      out1, W2p, Wsp, x, adjc, b2, b_skip, nullptr, out, nullptr, nullptr);
}